// Round 4
// baseline (389.391 us; speedup 1.0000x reference)
//
#include <hip/hip_runtime.h>

// spatial_encoding_block: B=65536, C=105, H=W=3
//   nearest-fill (mask from x[0,0,:,:]) -> depthwise 2x2 conv + bias
//   -> LeakyReLU(0.2) -> max over 2x2 -> + filled center -> [B,C] out.
// HBM floor: ~248 MB in + ~27.5 MB out => ~41 us at 6.7 TB/s.
// R4 PROBE: re-run se_kernel on a cold disjoint d_ws region (garbage data,
// valid map) to measure T_kernel as dur_us(R4) - dur_us(R3).

#define NC 105
#define GPB 512  // groups per block (4 waves x 128)

__global__ void se_map_kernel(const float* __restrict__ x,
                              unsigned long long* __restrict__ mapout) {
    bool mask[9];
    #pragma unroll
    for (int p = 0; p < 9; ++p) mask[p] = (x[p] == 0.0f);
    unsigned long long pk = 0;
    #pragma unroll
    for (int p = 0; p < 9; ++p) {
        int np = p;
        if (mask[p]) {
            int best = 0x7fffffff, bq = 0;
            const int pi = p / 3, pj = p % 3;
            for (int q = 0; q < 9; ++q) {
                if (mask[q]) continue;               // exclude zero pixels as sources
                const int qi = q / 3, qj = q % 3;
                const int d = (pi - qi) * (pi - qi) + (pj - qj) * (pj - qj);
                if (d < best) { best = d; bq = q; }  // ties -> lowest flat index
            }
            np = bq;
        }
        pk |= (unsigned long long)np << (4 * p);
    }
    *mapout = pk;
}

__global__ __launch_bounds__(256) void se_kernel(const float* __restrict__ x,
                                                 const float* __restrict__ w,
                                                 const float* __restrict__ b,
                                                 const unsigned long long* __restrict__ mapp,
                                                 float* __restrict__ out) {
    __shared__ float sx[GPB * 9];                    // 18432 B, partitioned per wave

    const int tid  = threadIdx.x;
    const int lane = tid & 63;
    const int wv   = tid >> 6;
    const int gbase = blockIdx.x * GPB;

    const float4* x4 = (const float4*)(x + (long long)gbase * 9);
    float4* sx4 = (float4*)sx;

    // wave-private staging: wave wv owns f4 range [wv*288, wv*288+288)
    const int fb = wv * 288;
    sx4[fb + lane]       = x4[fb + lane];
    sx4[fb + lane + 64]  = x4[fb + lane + 64];
    sx4[fb + lane + 128] = x4[fb + lane + 128];
    sx4[fb + lane + 192] = x4[fb + lane + 192];
    if (lane < 32) sx4[fb + lane + 256] = x4[fb + lane + 256];
    // no __syncthreads: each wave reads only its own slice.

    const unsigned long long pk = *mapp;
    int nr[9];
    #pragma unroll
    for (int p = 0; p < 9; ++p) nr[p] = (int)((pk >> (4 * p)) & 15);

    const float4* w4 = (const float4*)w;

    #pragma unroll
    for (int half = 0; half < 2; ++half) {
        const int gl   = wv * 128 + half * 64 + lane;
        const int gidx = gbase + gl;                 // = b*105 + c
        const int c    = gidx % NC;

        const float* a = &sx[gl * 9];
        float v[9];
        #pragma unroll
        for (int p = 0; p < 9; ++p) v[p] = a[nr[p]];

        const float4 wc = w4[c];
        const float bias = b[c];

        float y00 = fmaf(v[0], wc.x, fmaf(v[1], wc.y, fmaf(v[3], wc.z, v[4] * wc.w))) + bias;
        float y01 = fmaf(v[1], wc.x, fmaf(v[2], wc.y, fmaf(v[4], wc.z, v[5] * wc.w))) + bias;
        float y10 = fmaf(v[3], wc.x, fmaf(v[4], wc.y, fmaf(v[6], wc.z, v[7] * wc.w))) + bias;
        float y11 = fmaf(v[4], wc.x, fmaf(v[5], wc.y, fmaf(v[7], wc.z, v[8] * wc.w))) + bias;

        y00 = (y00 > 0.0f) ? y00 : 0.2f * y00;
        y01 = (y01 > 0.0f) ? y01 : 0.2f * y01;
        y10 = (y10 > 0.0f) ? y10 : 0.2f * y10;
        y11 = (y11 > 0.0f) ? y11 : 0.2f * y11;

        const float m = fmaxf(fmaxf(y00, y01), fmaxf(y10, y11));
        out[gidx] = m + v[4];
    }
}

extern "C" void kernel_launch(void* const* d_in, const int* in_sizes, int n_in,
                              void* d_out, int out_size, void* d_ws, size_t ws_size,
                              hipStream_t stream) {
    const float* x = (const float*)d_in[0];
    const float* w = (const float*)d_in[1];
    const float* b = (const float*)d_in[2];
    float* out = (float*)d_out;
    unsigned long long* map = (unsigned long long*)d_ws;

    const int n_groups = in_sizes[0] / 9;   // B*C = 6,881,280
    const int grid = n_groups / GPB;        // 13440 exactly

    se_map_kernel<<<1, 1, 0, stream>>>(x, map);
    se_kernel<<<grid, 256, 0, stream>>>(x, w, b, map, out);

    // PROBE: same kernel on a cold, disjoint ws region (values are poison,
    // map is valid so LDS indices stay in range). Measures T_kernel as the
    // dur_us delta vs R3. ws_size is constant across calls -> same work.
    if (ws_size >= ((size_t)320 << 20)) {
        const float* px = (const float*)d_ws;                              // 248 MB read
        float* pout = (float*)((char*)d_ws + ((size_t)280 << 20));         // 27.5 MB write
        se_kernel<<<grid, 256, 0, stream>>>(px, w, b, map, pout);
    }
}

// Round 5
// 327.912 us; speedup vs baseline: 1.1875x; 1.1875x over previous
//
#include <hip/hip_runtime.h>

// spatial_encoding_block: B=65536, C=105, H=W=3
//   nearest-fill (mask from x[0,0,:,:]) -> depthwise 2x2 conv + bias
//   -> LeakyReLU(0.2) -> max over 2x2 -> + filled center -> [B,C] out.
//
// ROOFLINE ACCOUNTING (measured R0-R4):
//   compulsory traffic: 248 MB read + 27.5 MB write = 275.6 MB
//   T_kernel ~= 49 us cold (R4 disjoint-region probe: dur delta +49.8 us)
//            => 5.6 TB/s ~= 84-89% of achievable streaming BW (6.3-6.7 TB/s)
//   dur_us ~= 336.6 = ~287 us fixed harness re-poison/restore + T_kernel.
//   All structural variants (barrier/no-barrier, 1-2 groups/thread,
//   map in-block vs pre-kernel) equal within noise -> pure streaming bound.

#define NC 105
#define GPB 512  // groups per block (256 threads x 2)

__global__ __launch_bounds__(256) void se_kernel(const float* __restrict__ x,
                                                 const float* __restrict__ w,
                                                 const float* __restrict__ b,
                                                 float* __restrict__ out) {
    __shared__ float sx[GPB * 9];                       // 18432 B
    __shared__ unsigned int s_nearpk[2] __attribute__((aligned(8)));

    const int tid = threadIdx.x;
    const int gbase = blockIdx.x * GPB;
    const float4* x4 = (const float4*)(x + (long long)gbase * 9);
    float4* sx4 = (float4*)sx;

    // ---- coalesced global->LDS staging: 1152 float4 per block ----
    sx4[tid]       = x4[tid];
    sx4[tid + 256] = x4[tid + 256];
    sx4[tid + 512] = x4[tid + 512];
    sx4[tid + 768] = x4[tid + 768];
    if (tid < 128) sx4[tid + 1024] = x4[tid + 1024];

    // ---- nearest-fill map from x[0,0,:,:], packed 4 bits/index ----
    if (tid == 0) {
        bool mask[9];
        #pragma unroll
        for (int p = 0; p < 9; ++p) mask[p] = (x[p] == 0.0f);
        unsigned int lo = 0, hi = 0;
        #pragma unroll
        for (int p = 0; p < 9; ++p) {
            int np = p;
            if (mask[p]) {
                int best = 0x7fffffff, bq = 0;
                const int pi = p / 3, pj = p % 3;
                for (int q = 0; q < 9; ++q) {
                    if (mask[q]) continue;               // exclude zero pixels as sources
                    const int qi = q / 3, qj = q % 3;
                    const int d = (pi - qi) * (pi - qi) + (pj - qj) * (pj - qj);
                    if (d < best) { best = d; bq = q; }  // ties -> lowest flat index
                }
                np = bq;
            }
            if (p < 8) lo |= (unsigned)np << (4 * p); else hi = (unsigned)np;
        }
        s_nearpk[0] = lo;
        s_nearpk[1] = hi;
    }
    __syncthreads();

    // one ds_read_b64 broadcast, then bfe extracts
    const unsigned int lo = s_nearpk[0];
    const unsigned int hi = s_nearpk[1];
    int nr[9];
    #pragma unroll
    for (int p = 0; p < 8; ++p) nr[p] = (lo >> (4 * p)) & 15;
    nr[8] = hi & 15;

    const float4* w4 = (const float4*)w;

    #pragma unroll
    for (int half = 0; half < 2; ++half) {
        const int gl = tid + half * 256;                // local group
        const int gidx = gbase + gl;                    // = b*105 + c
        const int c = gidx % NC;

        // LDS gather: lane stride 9 dwords (odd) -> 2 lanes/bank, free
        const float* a = &sx[gl * 9];
        float v[9];
        #pragma unroll
        for (int p = 0; p < 9; ++p) v[p] = a[nr[p]];

        const float4 wc = w4[c];
        const float bias = b[c];

        // depthwise 2x2 VALID conv on the filled 3x3 tile
        float y00 = fmaf(v[0], wc.x, fmaf(v[1], wc.y, fmaf(v[3], wc.z, v[4] * wc.w))) + bias;
        float y01 = fmaf(v[1], wc.x, fmaf(v[2], wc.y, fmaf(v[4], wc.z, v[5] * wc.w))) + bias;
        float y10 = fmaf(v[3], wc.x, fmaf(v[4], wc.y, fmaf(v[6], wc.z, v[7] * wc.w))) + bias;
        float y11 = fmaf(v[4], wc.x, fmaf(v[5], wc.y, fmaf(v[7], wc.z, v[8] * wc.w))) + bias;

        // LeakyReLU(0.2)
        y00 = (y00 > 0.0f) ? y00 : 0.2f * y00;
        y01 = (y01 > 0.0f) ? y01 : 0.2f * y01;
        y10 = (y10 > 0.0f) ? y10 : 0.2f * y10;
        y11 = (y11 > 0.0f) ? y11 : 0.2f * y11;

        const float m = fmaxf(fmaxf(y00, y01), fmaxf(y10, y11));
        out[gidx] = m + v[4];                           // + aug[:,:,1,1]
    }
}

extern "C" void kernel_launch(void* const* d_in, const int* in_sizes, int n_in,
                              void* d_out, int out_size, void* d_ws, size_t ws_size,
                              hipStream_t stream) {
    const float* x = (const float*)d_in[0];
    const float* w = (const float*)d_in[1];
    const float* b = (const float*)d_in[2];
    float* out = (float*)d_out;

    const int n_groups = in_sizes[0] / 9;   // B*C = 6,881,280
    const int grid = n_groups / GPB;        // 13440 exactly

    se_kernel<<<grid, 256, 0, stream>>>(x, w, b, out);
}